// Round 12
// baseline (325.564 us; speedup 1.0000x reference)
//
#include <hip/hip_runtime.h>
#include <math.h>

// Problem constants (from setup_inputs):
#define T_STEPS   4
#define NODE_NUM  10000
#define NUM_NODES 50000
#define E         256     // embedding dim
#define TWO_E     512
#define CC        128     // C
#define TWO_C     256
#define ROWS      32      // rows per tile (R8 proved 16 worse: B-load amortization)
#define NROWS_ALL (T_STEPS * NODE_NUM)
#define MAX_SLOTS 20000   // dup keys have >=2 rows each -> <= 40000/2 slots

typedef short bf16x8 __attribute__((ext_vector_type(8)));   // 8 bf16 = 4 VGPRs
typedef float f32x4  __attribute__((ext_vector_type(4)));   // MFMA accumulator
typedef unsigned short u16x4 __attribute__((ext_vector_type(4)));

#define MFMA16(a, b, c) __builtin_amdgcn_mfma_f32_16x16x32_bf16((a), (b), (c), 0, 0, 0)

// bf16 weights, transposed [N][K], module-scope device global.
// layout (elements): w1t @0 (512x256), w2t @131072 (128x512),
//                    w1ut @196608 (256x128), w2ut @229376 (256x256)
static __device__ unsigned short g_wt[294912];
// per-(t, idx) occurrence count; rows with cnt==1 (~82%) read x directly.
static __device__ int g_cnt[T_STEPS * NUM_NODES];
// per-key compact slot id (valid only when cnt>=2)
static __device__ int g_slot[T_STEPS * NUM_NODES];
static __device__ int g_nslots;
// compacted list of duplicate rows (single list)
static __device__ int g_dup[NROWS_ALL];
static __device__ int g_ndup0;

// tanh-form GELU (validated R7: absmax unchanged, VALUBusy 27->17%)
__device__ __forceinline__ float geluf(float v) {
    float p = v * (1.5957691216057308f + 0.07135481282636226f * v * v);
    return v / (1.0f + __expf(-p));
}

// fp32 -> bf16 round-to-nearest-even (finite inputs only)
__device__ __forceinline__ unsigned short f2bf(float f) {
    unsigned int u = __builtin_bit_cast(unsigned int, f);
    u += 0x7fffu + ((u >> 16) & 1u);
    return (unsigned short)(u >> 16);
}

// ---- weight prep: fp32 [K][N] -> bf16 [N][K]; zero cnt/counters/ctable ----
__global__ void prep_weights(float* __restrict__ ctable,
                             const float* __restrict__ W1d, const float* __restrict__ W2d,
                             const float* __restrict__ W1u, const float* __restrict__ W2u) {
    int i = blockIdx.x * 256 + threadIdx.x;       // 0 .. 200703
    if (i == 0) { g_nslots = 0; g_ndup0 = 0; }
    if (i < T_STEPS * NUM_NODES) g_cnt[i] = 0;    // 200000 counts
    {
        float4 z = make_float4(0.f, 0.f, 0.f, 0.f);
        float4* ct4 = reinterpret_cast<float4*>(ctable);
        for (int j = i; j < MAX_SLOTS * E / 4; j += 200704) ct4[j] = z;
    }
    if (i < 131072) {  // w1t: [512][256] <- W1d [256][512]
        int n = i >> 8, k = i & 255;
        g_wt[i] = f2bf(W1d[(size_t)k * TWO_E + n]);
    }
    if (i < 65536) {   // w2t: [128][512] <- W2d [512][128]
        int n = i >> 9, k = i & 511;
        g_wt[131072 + i] = f2bf(W2d[(size_t)k * CC + n]);
    }
    if (i < 32768) {   // w1ut: [256][128] <- W1u [128][256]
        int n = i >> 7, k = i & 127;
        g_wt[196608 + i] = f2bf(W1u[(size_t)k * TWO_C + n]);
    }
    if (i < 65536) {   // w2ut: [256][256] <- W2u [256][256]
        int n = i >> 8, k = i & 255;
        g_wt[229376 + i] = f2bf(W2u[(size_t)k * E + n]);
    }
}

// ---------------- count occurrences of each (t, idx) ----------------
__global__ void count_kernel(const int* __restrict__ indices) {
    int gr = blockIdx.x * 256 + threadIdx.x;
    if (gr < NROWS_ALL) {
        int t = gr / NODE_NUM;
        atomicAdd(&g_cnt[t * NUM_NODES + indices[gr]], 1);
    }
}

// ---- fused: per-key slot assignment + dup-row list compaction ----
__global__ void index_prep_kernel(const int* __restrict__ indices) {
    int i = blockIdx.x * 256 + threadIdx.x;       // 0 .. 200703
    if (i < T_STEPS * NUM_NODES && g_cnt[i] >= 2)
        g_slot[i] = atomicAdd(&g_nslots, 1);
    if (i < NROWS_ALL) {
        int t = i / NODE_NUM;
        if (g_cnt[t * NUM_NODES + indices[i]] >= 2) {
            int p = atomicAdd(&g_ndup0, 1);
            g_dup[p] = i;
        }
    }
}

// ---- scatter-add dup rows into the compact table, from the compacted list ----
__global__ void scatter_list_kernel(float* __restrict__ ctable,
                                    const float* __restrict__ x,
                                    const int* __restrict__ indices) {
    int nd = g_ndup0;
    for (int e = blockIdx.x; e < nd; e += gridDim.x) {
        int gr = g_dup[e];
        int t = gr / NODE_NUM;
        int slot = g_slot[t * NUM_NODES + indices[gr]];
        atomicAdd(&ctable[(size_t)slot * E + threadIdx.x],
                  x[(size_t)gr * E + threadIdx.x]);
    }
}

// ================= GEMM phase helpers (R9/R11 bodies, verbatim logic) =========
__device__ __forceinline__ void gemm1_phase(const unsigned short* Xs, unsigned short* H1,
                                            const unsigned short* w1t,
                                            const float* __restrict__ b1d,
                                            int w, int l16, int quad) {
    bf16x8 af[2][8];
    #pragma unroll
    for (int mt = 0; mt < 2; ++mt) {
        const unsigned short* base = Xs + (l16 + 16 * mt) * 264 + quad * 8;
        #pragma unroll
        for (int ks = 0; ks < 8; ++ks)
            af[mt][ks] = *reinterpret_cast<const bf16x8*>(base + ks * 32);
    }
    bf16x8 bbuf[2][8];
    {
        const unsigned short* bp = w1t + (size_t)((w * 8) * 16 + l16) * 256 + quad * 8;
        #pragma unroll
        for (int ks = 0; ks < 8; ++ks)
            bbuf[0][ks] = *reinterpret_cast<const bf16x8*>(bp + ks * 32);
    }
    #pragma unroll
    for (int nt_ = 0; nt_ < 8; ++nt_) {
        const int cb = nt_ & 1, nb = cb ^ 1;
        if (nt_ < 7) {
            const unsigned short* bp =
                w1t + (size_t)((w * 8 + nt_ + 1) * 16 + l16) * 256 + quad * 8;
            #pragma unroll
            for (int ks = 0; ks < 8; ++ks)
                bbuf[nb][ks] = *reinterpret_cast<const bf16x8*>(bp + ks * 32);
        }
        int n = (w * 8 + nt_) * 16 + l16;
        f32x4 a0 = {0.f, 0.f, 0.f, 0.f}, a1 = {0.f, 0.f, 0.f, 0.f};
        #pragma unroll
        for (int ks = 0; ks < 8; ++ks) {
            a0 = MFMA16(af[0][ks], bbuf[cb][ks], a0);
            a1 = MFMA16(af[1][ks], bbuf[cb][ks], a1);
        }
        float bias = b1d[n];
        #pragma unroll
        for (int reg = 0; reg < 4; ++reg) {
            int r = quad * 4 + reg;
            H1[r * 520 + n]        = f2bf(geluf(a0[reg] + bias));
            H1[(r + 16) * 520 + n] = f2bf(geluf(a1[reg] + bias));
        }
    }
}

__device__ __forceinline__ void gemm2_phase(const unsigned short* H1, float* H2f,
                                            const unsigned short* w2t,
                                            const float* __restrict__ b2d,
                                            int w, int l16, int quad) {
    f32x4 acc2[2][2];
    #pragma unroll
    for (int i = 0; i < 2; ++i)
        #pragma unroll
        for (int j = 0; j < 2; ++j) acc2[i][j] = (f32x4){0.f, 0.f, 0.f, 0.f};
    bf16x8 afk[2][8];
    #pragma unroll
    for (int mt = 0; mt < 2; ++mt) {
        const unsigned short* base = H1 + (l16 + 16 * mt) * 520 + quad * 8;
        #pragma unroll
        for (int ks = 0; ks < 8; ++ks)
            afk[mt][ks] = *reinterpret_cast<const bf16x8*>(base + ks * 32);
    }
    bf16x8 bbuf[2][8];
    {
        const unsigned short* bp = w2t + (size_t)((w * 2) * 16 + l16) * 512 + quad * 8;
        #pragma unroll
        for (int ks = 0; ks < 8; ++ks)
            bbuf[0][ks] = *reinterpret_cast<const bf16x8*>(bp + ks * 32);
    }
    #pragma unroll
    for (int s = 0; s < 4; ++s) {
        const int nt2 = s & 1;
        const int cb = s & 1, nb = cb ^ 1;
        if (s < 3) {
            const int s1 = s + 1, kh1 = s1 >> 1, nt21 = s1 & 1;
            const unsigned short* bp =
                w2t + (size_t)((w * 2 + nt21) * 16 + l16) * 512 + kh1 * 256 + quad * 8;
            #pragma unroll
            for (int ks = 0; ks < 8; ++ks)
                bbuf[nb][ks] = *reinterpret_cast<const bf16x8*>(bp + ks * 32);
        }
        if (s == 2) {
            #pragma unroll
            for (int mt = 0; mt < 2; ++mt) {
                const unsigned short* base = H1 + (l16 + 16 * mt) * 520 + 256 + quad * 8;
                #pragma unroll
                for (int ks = 0; ks < 8; ++ks)
                    afk[mt][ks] = *reinterpret_cast<const bf16x8*>(base + ks * 32);
            }
        }
        #pragma unroll
        for (int ks = 0; ks < 8; ++ks) {
            acc2[nt2][0] = MFMA16(afk[0][ks], bbuf[cb][ks], acc2[nt2][0]);
            acc2[nt2][1] = MFMA16(afk[1][ks], bbuf[cb][ks], acc2[nt2][1]);
        }
    }
    #pragma unroll
    for (int nt2 = 0; nt2 < 2; ++nt2) {
        int n = (w * 2 + nt2) * 16 + l16;
        float bias = b2d[n];
        #pragma unroll
        for (int mt = 0; mt < 2; ++mt)
            #pragma unroll
            for (int reg = 0; reg < 4; ++reg) {
                int r = mt * 16 + quad * 4 + reg;
                H2f[r * 132 + n] = acc2[nt2][mt][reg] + bias;
            }
    }
}

__device__ __forceinline__ void lnu_phase(const float* H2f, unsigned short* H2b,
                                          const float* __restrict__ lnu_s,
                                          const float* __restrict__ lnu_b, int tid) {
    int row = tid >> 3, l8 = tid & 7;
    float s = 0.f, sq = 0.f;
    #pragma unroll
    for (int k = 0; k < 16; ++k) {
        float v = H2f[row * 132 + k * 8 + l8];
        s += v; sq += v * v;
    }
    s  += __shfl_xor(s, 1);  s  += __shfl_xor(s, 2);  s  += __shfl_xor(s, 4);
    sq += __shfl_xor(sq, 1); sq += __shfl_xor(sq, 2); sq += __shfl_xor(sq, 4);
    float mu = s * (1.0f / CC);
    float var = sq * (1.0f / CC) - mu * mu;
    float rs = rsqrtf(var + 1e-5f);
    #pragma unroll
    for (int k = 0; k < 16; ++k) {
        int c = k * 8 + l8;
        float v = (H2f[row * 132 + c] - mu) * rs * lnu_s[c] + lnu_b[c];
        H2b[row * 136 + c] = f2bf(v);
    }
}

__device__ __forceinline__ void gemm3_phase(const unsigned short* H2b, unsigned short* G1,
                                            const unsigned short* w1ut,
                                            const float* __restrict__ b1u,
                                            int w, int l16, int quad) {
    bf16x8 af3[2][4];
    #pragma unroll
    for (int mt = 0; mt < 2; ++mt) {
        const unsigned short* base = H2b + (l16 + 16 * mt) * 136 + quad * 8;
        #pragma unroll
        for (int ks = 0; ks < 4; ++ks)
            af3[mt][ks] = *reinterpret_cast<const bf16x8*>(base + ks * 32);
    }
    bf16x8 bbuf[2][4];
    {
        const unsigned short* bp = w1ut + (size_t)((w * 4) * 16 + l16) * 128 + quad * 8;
        #pragma unroll
        for (int ks = 0; ks < 4; ++ks)
            bbuf[0][ks] = *reinterpret_cast<const bf16x8*>(bp + ks * 32);
    }
    #pragma unroll
    for (int nt_ = 0; nt_ < 4; ++nt_) {
        const int cb = nt_ & 1, nb = cb ^ 1;
        if (nt_ < 3) {
            const unsigned short* bp =
                w1ut + (size_t)((w * 4 + nt_ + 1) * 16 + l16) * 128 + quad * 8;
            #pragma unroll
            for (int ks = 0; ks < 4; ++ks)
                bbuf[nb][ks] = *reinterpret_cast<const bf16x8*>(bp + ks * 32);
        }
        int n = (w * 4 + nt_) * 16 + l16;
        f32x4 a0 = {0.f, 0.f, 0.f, 0.f}, a1 = {0.f, 0.f, 0.f, 0.f};
        #pragma unroll
        for (int ks = 0; ks < 4; ++ks) {
            a0 = MFMA16(af3[0][ks], bbuf[cb][ks], a0);
            a1 = MFMA16(af3[1][ks], bbuf[cb][ks], a1);
        }
        float bias = b1u[n];
        #pragma unroll
        for (int reg = 0; reg < 4; ++reg) {
            int r = quad * 4 + reg;
            G1[r * 264 + n]        = f2bf(geluf(a0[reg] + bias));
            G1[(r + 16) * 264 + n] = f2bf(geluf(a1[reg] + bias));
        }
    }
}

__device__ __forceinline__ void gemm4_phase(const unsigned short* G1,
                                            const unsigned short* w2ut,
                                            const float* __restrict__ b2u,
                                            float* __restrict__ out,
                                            int grb, int grLim, int w, int l16, int quad) {
    bf16x8 af4[2][8];
    #pragma unroll
    for (int mt = 0; mt < 2; ++mt) {
        const unsigned short* base = G1 + (l16 + 16 * mt) * 264 + quad * 8;
        #pragma unroll
        for (int ks = 0; ks < 8; ++ks)
            af4[mt][ks] = *reinterpret_cast<const bf16x8*>(base + ks * 32);
    }
    bf16x8 bbuf[2][8];
    {
        const unsigned short* bp = w2ut + (size_t)((w * 4) * 16 + l16) * 256 + quad * 8;
        #pragma unroll
        for (int ks = 0; ks < 8; ++ks)
            bbuf[0][ks] = *reinterpret_cast<const bf16x8*>(bp + ks * 32);
    }
    #pragma unroll
    for (int nt_ = 0; nt_ < 4; ++nt_) {
        const int cb = nt_ & 1, nb = cb ^ 1;
        if (nt_ < 3) {
            const unsigned short* bp =
                w2ut + (size_t)((w * 4 + nt_ + 1) * 16 + l16) * 256 + quad * 8;
            #pragma unroll
            for (int ks = 0; ks < 8; ++ks)
                bbuf[nb][ks] = *reinterpret_cast<const bf16x8*>(bp + ks * 32);
        }
        int n = (w * 4 + nt_) * 16 + l16;
        f32x4 a0 = {0.f, 0.f, 0.f, 0.f}, a1 = {0.f, 0.f, 0.f, 0.f};
        #pragma unroll
        for (int ks = 0; ks < 8; ++ks) {
            a0 = MFMA16(af4[0][ks], bbuf[cb][ks], a0);
            a1 = MFMA16(af4[1][ks], bbuf[cb][ks], a1);
        }
        float bias = b2u[n];
        #pragma unroll
        for (int reg = 0; reg < 4; ++reg) {
            int r = quad * 4 + reg;
            int g0 = grb + r, g1 = grb + r + 16;
            if (g0 < grLim) out[(size_t)g0 * E + n] = a0[reg] + bias;
            if (g1 < grLim) out[(size_t)g1 * E + n] = a1[reg] + bias;
        }
    }
}

// reg-staged gather issue: stg[it] = rowsrc + batched_x for tile rows (wave-per-row)
__device__ __forceinline__ void stage_gather(float4* stg, const float* const* rptr,
                                             const int* ridx, const float* __restrict__ bx,
                                             int base, int w, int c4) {
    #pragma unroll
    for (int it = 0; it < 8; ++it) {
        int r = base + it * 4 + w;
        float4 tv = *reinterpret_cast<const float4*>(rptr[r] + c4);
        float4 bv = *reinterpret_cast<const float4*>(&bx[(size_t)ridx[r] * E + c4]);
        float4 s; s.x = tv.x + bv.x; s.y = tv.y + bv.y; s.z = tv.z + bv.z; s.w = tv.w + bv.w;
        stg[it] = s;
    }
}

// wave-per-row LN_d from staged regs -> bf16 Xs
__device__ __forceinline__ void lnd_from_regs(const float4* stg, unsigned short* Xs,
                                              const float* __restrict__ lnd_s,
                                              const float* __restrict__ lnd_b,
                                              int w, int c4) {
    const float4 sc = *reinterpret_cast<const float4*>(lnd_s + c4);
    const float4 bi = *reinterpret_cast<const float4*>(lnd_b + c4);
    #pragma unroll
    for (int it = 0; it < 8; ++it) {
        const int r = it * 4 + w;
        float4 a = stg[it];
        float s  = a.x + a.y + a.z + a.w;
        float sq = a.x*a.x + a.y*a.y + a.z*a.z + a.w*a.w;
        #pragma unroll
        for (int m = 1; m < 64; m <<= 1) {
            s  += __shfl_xor(s,  m);
            sq += __shfl_xor(sq, m);
        }
        const float mu = s * (1.0f / E);
        const float rs = rsqrtf(sq * (1.0f / E) - mu * mu + 1e-5f);
        u16x4 o;
        o.x = f2bf((a.x - mu) * rs * sc.x + bi.x);
        o.y = f2bf((a.y - mu) * rs * sc.y + bi.y);
        o.z = f2bf((a.z - mu) * rs * sc.z + bi.z);
        o.w = f2bf((a.w - mu) * rs * sc.w + bi.w);
        *reinterpret_cast<u16x4*>(&Xs[r * 264 + c4]) = o;
    }
}

// ---------------- fused 2-tile pipelined MLP ----------------
// R12: grid 625; each block runs tiles b and b+625 through the 7-phase chain,
// software-pipelined: tile-1's gather (random-row HBM reads) is issued into
// registers during tile-0's LN_u and its LN_d runs inside tile-0's GEMM3 phase
// (write Xs directly; Xf eliminated for both tiles via wave-per-row reg LN).
// LDS map unchanged (R9/R11, 50.7KB, 3 blocks/CU):
//   region A [0, 33280):     H1 bf16 [32][520] / H2b bf16 [32][136] @0
//                            / G1 bf16 [32][264] @8704
//   region B [33280, 50176): Xs bf16 [32][264] / H2f f32 [32][132]
// Per-phase peak VGPR: GEMM2 ~150 (stg not live); stg (32) live only LN_u->G3.
__global__ __launch_bounds__(256, 3)
void mlp_kernel(const float* __restrict__ ctable,
                const float* __restrict__ x,
                const float* __restrict__ batched_x,
                const int* __restrict__ indices,
                const float* __restrict__ lnd_s, const float* __restrict__ lnd_b,
                const float* __restrict__ b1d, const float* __restrict__ b2d,
                const float* __restrict__ lnu_s, const float* __restrict__ lnu_b,
                const float* __restrict__ b1u, const float* __restrict__ b2u,
                float* __restrict__ out,
                int grLim) {
    __shared__ __align__(16) unsigned char smem[50176];
    __shared__ const float* rptr[2 * ROWS];
    __shared__ int    ridx[2 * ROWS];

    unsigned short* H1  = (unsigned short*)smem;                // [32][520] region A
    unsigned short* H2b = (unsigned short*)smem;                // [32][136] region A
    unsigned short* G1  = (unsigned short*)(smem + 8704);       // [32][264] region A
    unsigned short* Xs  = (unsigned short*)(smem + 33280);      // [32][264] region B
    float*          H2f = (float*)(smem + 33280);               // [32][132] region B

    const unsigned short* w1t  = g_wt;
    const unsigned short* w2t  = g_wt + 131072;
    const unsigned short* w1ut = g_wt + 196608;
    const unsigned short* w2ut = g_wt + 229376;

    const int tid = threadIdx.x;
    const int w = tid >> 6, lane = tid & 63;
    const int l16 = lane & 15, quad = lane >> 4;
    const int c4 = lane * 4;
    const int tile0 = blockIdx.x;
    const int tile1 = blockIdx.x + (int)gridDim.x;
    const int grb0 = tile0 * ROWS;
    const int grb1 = tile1 * ROWS;

    // P1: row setup for BOTH tiles, then tile-0 gather+LN_d -> Xs
    if (tid < 2 * ROWS) {
        int gr = ((tid < ROWS) ? grb0 : grb1) + (tid & (ROWS - 1));
        if (gr >= grLim) gr = grLim - 1;     // never taken (40000 rows exact); safety
        int t = gr / NODE_NUM;
        int key = t * NUM_NODES + indices[gr];
        ridx[tid] = indices[gr];
        rptr[tid] = (g_cnt[key] > 1)
            ? (ctable + (size_t)g_slot[key] * E)
            : (x + (size_t)gr * E);
    }
    __syncthreads();
    {
        float4 stg0[8];
        stage_gather(stg0, rptr, ridx, batched_x, 0, w, c4);
        lnd_from_regs(stg0, Xs, lnd_s, lnd_b, w, c4);
    }
    __syncthreads();                 // Xs(T0) ready

    // P2: GEMM1 T0 (Xs -> H1, region A previously empty)
    gemm1_phase(Xs, H1, w1t, b1d, w, l16, quad);
    __syncthreads();                 // H1 ready; Xs readers done

    // P3: GEMM2 T0 (H1 -> H2f over dead Xs)
    gemm2_phase(H1, H2f, w2t, b2d, w, l16, quad);
    __syncthreads();                 // H2f ready; H1 readers done

    // P4: LN_u T0 (H2f -> H2b over dead H1 head) + ISSUE tile-1 gather into regs
    float4 stg1[8];
    stage_gather(stg1, rptr, ridx, batched_x, ROWS, w, c4);   // overlapped loads
    lnu_phase(H2f, H2b, lnu_s, lnu_b, tid);
    __syncthreads();                 // H2b ready; H2f readers done

    // P5: GEMM3 T0 (H2b -> G1) + LN_d T1 from regs -> Xs (region B, dead)
    gemm3_phase(H2b, G1, w1ut, b1u, w, l16, quad);
    lnd_from_regs(stg1, Xs, lnd_s, lnd_b, w, c4);
    __syncthreads();                 // G1 ready; Xs(T1) ready

    // P6: GEMM4 T0 (G1 -> out rows of tile0)
    gemm4_phase(G1, w2ut, b2u, out, grb0, grLim, w, l16, quad);
    __syncthreads();                 // region A readers (af4) done

    // P7..P11: tile-1 chain (identical structure)
    gemm1_phase(Xs, H1, w1t, b1d, w, l16, quad);
    __syncthreads();
    gemm2_phase(H1, H2f, w2t, b2d, w, l16, quad);
    __syncthreads();
    lnu_phase(H2f, H2b, lnu_s, lnu_b, tid);
    __syncthreads();
    gemm3_phase(H2b, G1, w1ut, b1u, w, l16, quad);
    __syncthreads();
    gemm4_phase(G1, w2ut, b2u, out, grb1, grLim, w, l16, quad);
}

extern "C" void kernel_launch(void* const* d_in, const int* in_sizes, int n_in,
                              void* d_out, int out_size, void* d_ws, size_t ws_size,
                              hipStream_t stream) {
    const float* x     = (const float*)d_in[0];
    const float* bx    = (const float*)d_in[1];
    const int*   idxp  = (const int*)  d_in[2];
    const float* lnd_s = (const float*)d_in[3];
    const float* lnd_b = (const float*)d_in[4];
    const float* W1d   = (const float*)d_in[5];
    const float* b1d   = (const float*)d_in[6];
    const float* W2d   = (const float*)d_in[7];
    const float* b2d   = (const float*)d_in[8];
    const float* lnu_s = (const float*)d_in[9];
    const float* lnu_b = (const float*)d_in[10];
    const float* W1u   = (const float*)d_in[11];
    const float* b1u   = (const float*)d_in[12];
    const float* W2u   = (const float*)d_in[13];
    const float* b2u   = (const float*)d_in[14];
    float* out = (float*)d_out;
    float* ctable = (float*)d_ws;    // compact dup-sum table: 20.48 MB
    (void)ws_size; (void)in_sizes; (void)n_in; (void)out_size;

    prep_weights<<<784, 256, 0, stream>>>(ctable, W1d, W2d, W1u, W2u);
    count_kernel<<<(NROWS_ALL + 255) / 256, 256, 0, stream>>>(idxp);
    index_prep_kernel<<<784, 256, 0, stream>>>(idxp);
    scatter_list_kernel<<<1024, E, 0, stream>>>(ctable, x, idxp);
    mlp_kernel<<<NROWS_ALL / ROWS / 2, 256, 0, stream>>>(
        ctable, x, bx, idxp, lnd_s, lnd_b, b1d, b2d,
        lnu_s, lnu_b, b1u, b2u, out, NROWS_ALL);
}